// Round 1
// baseline (540.698 us; speedup 1.0000x reference)
//
#include <hip/hip_runtime.h>

// ---------------------------------------------------------------------------
// 2-layer GAT (H=2, D=64, Fin=128) on MI355X. fp32 throughout.
// Pipeline per launch:
//   CSR build (shared by both layers): count -> scan(3k) -> fill
//   layer0: gemm<128> -> attn_coeff -> aggregate(LN+ReLU) -> h
//   layer1: gemm<64>  -> attn_coeff -> aggregate(plain)  -> d_out
// ---------------------------------------------------------------------------

__global__ __launch_bounds__(256) void count_deg(const int* __restrict__ dst,
                                                 int* __restrict__ counts, int E) {
    int i = blockIdx.x * blockDim.x + threadIdx.x;
    if (i < E) atomicAdd(&counts[dst[i]], 1);
}

__global__ __launch_bounds__(1024) void scan1(const int* __restrict__ counts,
                                              int* __restrict__ excl,
                                              int* __restrict__ bsum, int N) {
    __shared__ int s[1024];
    int tid = threadIdx.x;
    int gid = blockIdx.x * 1024 + tid;
    int v = (gid < N) ? counts[gid] : 0;
    s[tid] = v;
    __syncthreads();
    for (int off = 1; off < 1024; off <<= 1) {
        int t = (tid >= off) ? s[tid - off] : 0;
        __syncthreads();
        s[tid] += t;
        __syncthreads();
    }
    if (gid < N) excl[gid] = s[tid] - v;           // exclusive scan within block
    if (tid == 1023) bsum[blockIdx.x] = s[1023];   // block total
}

__global__ __launch_bounds__(1024) void scan2(int* __restrict__ bsum, int nb) {
    __shared__ int s[1024];
    int tid = threadIdx.x;
    int v = (tid < nb) ? bsum[tid] : 0;
    s[tid] = v;
    __syncthreads();
    for (int off = 1; off < 1024; off <<= 1) {
        int t = (tid >= off) ? s[tid - off] : 0;
        __syncthreads();
        s[tid] += t;
        __syncthreads();
    }
    if (tid < nb) bsum[tid] = s[tid] - v;          // exclusive block offsets
}

__global__ __launch_bounds__(1024) void scan3(int* __restrict__ excl_inout,
                                              const int* __restrict__ bsum,
                                              int* __restrict__ cursor, int N, int E) {
    int gid = blockIdx.x * 1024 + threadIdx.x;
    if (gid < N) {
        int v = excl_inout[gid] + bsum[blockIdx.x];
        excl_inout[gid] = v;   // row_start
        cursor[gid] = v;
    }
    if (gid == 0) excl_inout[N] = E;
}

__global__ __launch_bounds__(256) void fill_edges(const int* __restrict__ src,
                                                  const int* __restrict__ dst,
                                                  int* __restrict__ cursor,
                                                  int* __restrict__ esrc, int E) {
    int i = blockIdx.x * blockDim.x + threadIdx.x;
    if (i < E) {
        int p = atomicAdd(&cursor[dst[i]], 1);
        esrc[p] = src[i];
    }
}

// Z[N,128] = X[N,K] @ W[K,128].  64-row block, BK=64 staging, 4x8 micro-tile.
template <int K>
__global__ __launch_bounds__(256) void gemm_k(const float* __restrict__ X,
                                              const float* __restrict__ W,
                                              float* __restrict__ Z, int N) {
    __shared__ float Ws[64 * 128];     // 32 KB
    __shared__ float Xs[64 * 65];      // 16.25 KB (+1 pad: 2-way bank alias, free)
    const int tid = threadIdx.x;
    const int row0 = blockIdx.x * 64;
    const int ty = tid / 16, tx = tid % 16;  // 16x16 threads, micro 4 rows x 8 cols

    float acc[4][8] = {};
    for (int k0 = 0; k0 < K; k0 += 64) {
        for (int i = tid; i < 64 * 128; i += 256) Ws[i] = W[k0 * 128 + i];
        for (int i = tid; i < 64 * 64; i += 256) {
            int r = i >> 6, c = i & 63;
            int gr = row0 + r;
            Xs[r * 65 + c] = (gr < N) ? X[(size_t)gr * K + k0 + c] : 0.f;
        }
        __syncthreads();
        for (int k = 0; k < 64; ++k) {
            float a0 = Xs[(ty * 4 + 0) * 65 + k];
            float a1 = Xs[(ty * 4 + 1) * 65 + k];
            float a2 = Xs[(ty * 4 + 2) * 65 + k];
            float a3 = Xs[(ty * 4 + 3) * 65 + k];
            const float4* wr = (const float4*)&Ws[k * 128 + tx * 8];
            float4 blo = wr[0], bhi = wr[1];
            float bb[8] = {blo.x, blo.y, blo.z, blo.w, bhi.x, bhi.y, bhi.z, bhi.w};
            float aa[4] = {a0, a1, a2, a3};
#pragma unroll
            for (int i = 0; i < 4; ++i)
#pragma unroll
                for (int j = 0; j < 8; ++j) acc[i][j] += aa[i] * bb[j];
        }
        __syncthreads();
    }
#pragma unroll
    for (int i = 0; i < 4; ++i) {
        int gr = row0 + ty * 4 + i;
        if (gr < N) {
            float4* zp = (float4*)&Z[(size_t)gr * 128 + tx * 8];
            zp[0] = make_float4(acc[i][0], acc[i][1], acc[i][2], acc[i][3]);
            zp[1] = make_float4(acc[i][4], acc[i][5], acc[i][6], acc[i][7]);
        }
    }
}

// el[n,h] = dot(z[n,h,:], a_l[h,:]),  er likewise.  One wave per node.
__global__ __launch_bounds__(256) void attn_coeff(const float* __restrict__ Z,
                                                  const float* __restrict__ al,
                                                  const float* __restrict__ ar,
                                                  float* __restrict__ el,
                                                  float* __restrict__ er, int N) {
    int wv = (blockIdx.x * blockDim.x + threadIdx.x) >> 6;
    int lane = threadIdx.x & 63;
    if (wv >= N) return;
    float z0 = Z[(size_t)wv * 128 + lane];
    float z1 = Z[(size_t)wv * 128 + 64 + lane];
    float pl0 = z0 * al[lane];
    float pl1 = z1 * al[64 + lane];
    float pr0 = z0 * ar[lane];
    float pr1 = z1 * ar[64 + lane];
    for (int off = 32; off; off >>= 1) {
        pl0 += __shfl_xor(pl0, off);
        pl1 += __shfl_xor(pl1, off);
        pr0 += __shfl_xor(pr0, off);
        pr1 += __shfl_xor(pr1, off);
    }
    if (lane == 0) {
        el[2 * wv] = pl0;
        el[2 * wv + 1] = pl1;
        er[2 * wv] = pr0;
        er[2 * wv + 1] = pr1;
    }
}

// One wave per dst node: edge softmax + weighted gather + head-mean (+LN+ReLU).
__global__ __launch_bounds__(256) void aggregate(
    const float* __restrict__ Z, const float* __restrict__ el,
    const float* __restrict__ er, const int* __restrict__ row_start,
    const int* __restrict__ esrc, const float* __restrict__ bias,
    const float* __restrict__ gamma, const float* __restrict__ beta,
    float* __restrict__ out, int N, int do_ln) {
    int wv = (blockIdx.x * blockDim.x + threadIdx.x) >> 6;
    int lane = threadIdx.x & 63;
    if (wv >= N) return;
    int s0 = row_start[wv], s1 = row_start[wv + 1];
    float er0 = er[2 * wv], er1 = er[2 * wv + 1];

    // pass 1: denominators
    float denom0 = 0.f, denom1 = 0.f;
    for (int base = s0; base < s1; base += 64) {
        int idx = base + lane;
        float w0 = 0.f, w1 = 0.f;
        if (idx < s1) {
            int sv = esrc[idx];
            float e0 = el[2 * sv] + er0;
            e0 = e0 > 0.f ? e0 : 0.2f * e0;
            float e1 = el[2 * sv + 1] + er1;
            e1 = e1 > 0.f ? e1 : 0.2f * e1;
            w0 = __expf(e0);
            w1 = __expf(e1);
        }
        float t0 = w0, t1 = w1;
        for (int off = 32; off; off >>= 1) {
            t0 += __shfl_xor(t0, off);
            t1 += __shfl_xor(t1, off);
        }
        denom0 += t0;
        denom1 += t1;
    }
    float inv0 = denom0 > 0.f ? 1.f / denom0 : 0.f;
    float inv1 = denom1 > 0.f ? 1.f / denom1 : 0.f;

    // pass 2: weighted gather
    float acc0 = 0.f, acc1 = 0.f;
    for (int base = s0; base < s1; base += 64) {
        int idx = base + lane;
        int sv = 0;
        float w0 = 0.f, w1 = 0.f;
        if (idx < s1) {
            sv = esrc[idx];
            float e0 = el[2 * sv] + er0;
            e0 = e0 > 0.f ? e0 : 0.2f * e0;
            float e1 = el[2 * sv + 1] + er1;
            e1 = e1 > 0.f ? e1 : 0.2f * e1;
            w0 = __expf(e0);
            w1 = __expf(e1);
        }
        int m = min(64, s1 - base);
        for (int j = 0; j < m; ++j) {
            int svj = __shfl(sv, j);
            float a0 = __shfl(w0, j) * inv0;
            float a1 = __shfl(w1, j) * inv1;
            acc0 += a0 * Z[(size_t)svj * 128 + lane];
            acc1 += a1 * Z[(size_t)svj * 128 + 64 + lane];
        }
    }

    // epilogue: head mean + bias, then optional LayerNorm+ReLU
    float m0 = (acc0 + acc1) * 0.5f + 0.5f * (bias[lane] + bias[64 + lane]);
    if (do_ln) {
        float s = m0;
        for (int off = 32; off; off >>= 1) s += __shfl_xor(s, off);
        float mu = s * (1.f / 64.f);
        float d = m0 - mu;
        float v = d * d;
        for (int off = 32; off; off >>= 1) v += __shfl_xor(v, off);
        float rstd = rsqrtf(v * (1.f / 64.f) + 1e-5f);
        float y = d * rstd * gamma[lane] + beta[lane];
        out[(size_t)wv * 64 + lane] = y > 0.f ? y : 0.f;
    } else {
        out[(size_t)wv * 64 + lane] = m0;
    }
}

extern "C" void kernel_launch(void* const* d_in, const int* in_sizes, int n_in,
                              void* d_out, int out_size, void* d_ws, size_t ws_size,
                              hipStream_t stream) {
    const float* feat = (const float*)d_in[0];
    const int* src = (const int*)d_in[1];
    const int* dst = (const int*)d_in[2];
    const float* W1 = (const float*)d_in[3];
    const float* al1 = (const float*)d_in[4];
    const float* ar1 = (const float*)d_in[5];
    const float* b1 = (const float*)d_in[6];
    const float* gamma1 = (const float*)d_in[7];
    const float* beta1 = (const float*)d_in[8];
    const float* W2 = (const float*)d_in[9];
    const float* al2 = (const float*)d_in[10];
    const float* ar2 = (const float*)d_in[11];
    const float* b2 = (const float*)d_in[12];

    const int N = in_sizes[0] / 128;
    const int E = in_sizes[1];

    float* ws = (float*)d_ws;
    float* Z = ws;                              // N*128
    float* h = Z + (size_t)N * 128;             // N*64
    float* el = h + (size_t)N * 64;             // 2N
    float* er = el + 2 * (size_t)N;             // 2N
    int* counts = (int*)(er + 2 * (size_t)N);   // N
    int* row_start = counts + N;                // N+1
    int* cursor = row_start + N + 1;            // N
    int* bsum = cursor + N;                     // 1024
    int* esrc = bsum + 1024;                    // E

    const int nb = (N + 1023) / 1024;

    // ---- CSR build (shared by both layers) ----
    hipMemsetAsync(counts, 0, sizeof(int) * N, stream);
    count_deg<<<(E + 255) / 256, 256, 0, stream>>>(dst, counts, E);
    scan1<<<nb, 1024, 0, stream>>>(counts, row_start, bsum, N);
    scan2<<<1, 1024, 0, stream>>>(bsum, nb);
    scan3<<<nb, 1024, 0, stream>>>(row_start, bsum, cursor, N, E);
    fill_edges<<<(E + 255) / 256, 256, 0, stream>>>(src, dst, cursor, esrc, E);

    // ---- layer 0 ----
    gemm_k<128><<<(N + 63) / 64, 256, 0, stream>>>(feat, W1, Z, N);
    attn_coeff<<<(N + 3) / 4, 256, 0, stream>>>(Z, al1, ar1, el, er, N);
    aggregate<<<(N + 3) / 4, 256, 0, stream>>>(Z, el, er, row_start, esrc, b1,
                                               gamma1, beta1, h, N, 1);

    // ---- layer 1 ----
    gemm_k<64><<<(N + 63) / 64, 256, 0, stream>>>(h, W2, Z, N);
    attn_coeff<<<(N + 3) / 4, 256, 0, stream>>>(Z, al2, ar2, el, er, N);
    aggregate<<<(N + 3) / 4, 256, 0, stream>>>(Z, el, er, row_start, esrc, b2,
                                               nullptr, nullptr, (float*)d_out, N, 0);
}

// Round 2
// 457.375 us; speedup vs baseline: 1.1822x; 1.1822x over previous
//
#include <hip/hip_runtime.h>

// ---------------------------------------------------------------------------
// 2-layer GAT (H=2, D=64, Fin=128) on MI355X.
// bf16 MFMA GEMMs, packed-bf16 Z table for the edge gather, fp32 accumulate.
//   cast: feat->bf16, W1/W2 -> bf16 transposed
//   CSR build (shared): count -> scan(3k) -> fill
//   layer0: gemm_mfma<128> -> attn_coeff -> aggregate(LN+ReLU, bf16 out) -> h
//   layer1: gemm_mfma<64>  -> attn_coeff -> aggregate(plain, fp32 out) -> d_out
// ---------------------------------------------------------------------------

typedef __attribute__((ext_vector_type(8))) short short8;
typedef __attribute__((ext_vector_type(8))) unsigned short ushort8;
typedef __attribute__((ext_vector_type(4))) float f32x4;

__device__ inline unsigned int f2bf(float x) {
    unsigned int u = __builtin_bit_cast(unsigned int, x);
    return (u + 0x7fffu + ((u >> 16) & 1u)) >> 16;   // RNE
}
__device__ inline float bf2f(unsigned int b) {
    return __builtin_bit_cast(float, b << 16);
}

// ---------------- casts ----------------
__global__ __launch_bounds__(256) void cast_feat(const float* __restrict__ in,
                                                 unsigned short* __restrict__ out,
                                                 int n4) {  // n/4 groups
    int i = blockIdx.x * blockDim.x + threadIdx.x;
    if (i < n4) {
        float4 v = ((const float4*)in)[i];
        unsigned short o0 = (unsigned short)f2bf(v.x);
        unsigned short o1 = (unsigned short)f2bf(v.y);
        unsigned short o2 = (unsigned short)f2bf(v.z);
        unsigned short o3 = (unsigned short)f2bf(v.w);
        ushort4 o = {o0, o1, o2, o3};
        ((ushort4*)out)[i] = o;
    }
}

// W[K,128] fp32 -> Wt[128,K] bf16 (transposed for MFMA B-fragment reads)
__global__ __launch_bounds__(256) void cast_w_t(const float* __restrict__ W,
                                                unsigned short* __restrict__ Wt,
                                                int K) {
    int i = blockIdx.x * blockDim.x + threadIdx.x;
    if (i < K * 128) {
        int k = i >> 7, c = i & 127;
        Wt[c * K + k] = (unsigned short)f2bf(W[i]);
    }
}

// ---------------- CSR build ----------------
__global__ __launch_bounds__(256) void count_deg(const int* __restrict__ dst,
                                                 int* __restrict__ counts, int E) {
    int i = blockIdx.x * blockDim.x + threadIdx.x;
    if (i < E) atomicAdd(&counts[dst[i]], 1);
}

__global__ __launch_bounds__(1024) void scan1(const int* __restrict__ counts,
                                              int* __restrict__ excl,
                                              int* __restrict__ bsum, int N) {
    __shared__ int s[1024];
    int tid = threadIdx.x;
    int gid = blockIdx.x * 1024 + tid;
    int v = (gid < N) ? counts[gid] : 0;
    s[tid] = v;
    __syncthreads();
    for (int off = 1; off < 1024; off <<= 1) {
        int t = (tid >= off) ? s[tid - off] : 0;
        __syncthreads();
        s[tid] += t;
        __syncthreads();
    }
    if (gid < N) excl[gid] = s[tid] - v;
    if (tid == 1023) bsum[blockIdx.x] = s[1023];
}

__global__ __launch_bounds__(1024) void scan2(int* __restrict__ bsum, int nb) {
    __shared__ int s[1024];
    int tid = threadIdx.x;
    int v = (tid < nb) ? bsum[tid] : 0;
    s[tid] = v;
    __syncthreads();
    for (int off = 1; off < 1024; off <<= 1) {
        int t = (tid >= off) ? s[tid - off] : 0;
        __syncthreads();
        s[tid] += t;
        __syncthreads();
    }
    if (tid < nb) bsum[tid] = s[tid] - v;
}

__global__ __launch_bounds__(1024) void scan3(int* __restrict__ excl_inout,
                                              const int* __restrict__ bsum,
                                              int* __restrict__ cursor, int N, int E) {
    int gid = blockIdx.x * 1024 + threadIdx.x;
    if (gid < N) {
        int v = excl_inout[gid] + bsum[blockIdx.x];
        excl_inout[gid] = v;
        cursor[gid] = v;
    }
    if (gid == 0) excl_inout[N] = E;
}

__global__ __launch_bounds__(256) void fill_edges(const int* __restrict__ src,
                                                  const int* __restrict__ dst,
                                                  int* __restrict__ cursor,
                                                  int* __restrict__ esrc, int E) {
    int i = blockIdx.x * blockDim.x + threadIdx.x;
    if (i < E) {
        int p = atomicAdd(&cursor[dst[i]], 1);
        esrc[p] = src[i];
    }
}

// ---------------- MFMA GEMM ----------------
// Zg[n][f] = pack(bf16(z[n][f]), bf16(z[n][64+f])), f in [0,64).
// Xb: [N,K] bf16.  Wt: [128,K] bf16 (col-major of original W).
// Block: 256 thr = 4 waves, 64 rows. Each wave: 16 rows x 128 cols,
// 8 col-tiles of 16x16x32 MFMA.
template <int K>
__global__ __launch_bounds__(256) void gemm_mfma(const unsigned short* __restrict__ Xb,
                                                 const unsigned short* __restrict__ Wt,
                                                 unsigned int* __restrict__ Zg,
                                                 int N) {
    constexpr int LDX = K + 8;                 // pad: 2-way bank alias (free)
    __shared__ unsigned short Ws[128 * LDX];   // K=128: 34 KB, K=64: 18 KB
    __shared__ unsigned short Xs[64 * LDX];    // K=128: 17 KB, K=64:  9 KB
    const int tid = threadIdx.x;
    const int row0 = blockIdx.x * 64;

    // stage W (all 128 output cols x K), ushort8 vectors
    constexpr int KC = K / 8;
    for (int i = tid; i < 128 * KC; i += 256) {
        int r = i / KC, c8 = i % KC;
        ushort8 v = *(const ushort8*)&Wt[r * K + c8 * 8];
        *(ushort8*)&Ws[r * LDX + c8 * 8] = v;
    }
    // stage X tile (64 rows); clamp OOB rows to row 0 (outputs guarded later)
    for (int i = tid; i < 64 * KC; i += 256) {
        int r = i / KC, c8 = i % KC;
        int gr = row0 + r;
        int sr = (gr < N) ? gr : 0;
        ushort8 v = *(const ushort8*)&Xb[(size_t)sr * K + c8 * 8];
        *(ushort8*)&Xs[r * LDX + c8 * 8] = v;
    }
    __syncthreads();

    const int wv = tid >> 6, lane = tid & 63;
    const int m = lane & 15, q = lane >> 4;

    f32x4 acc[8];
#pragma unroll
    for (int t = 0; t < 8; ++t) {
        acc[t][0] = 0.f; acc[t][1] = 0.f; acc[t][2] = 0.f; acc[t][3] = 0.f;
    }

    const int arow = wv * 16 + m;
#pragma unroll
    for (int k0 = 0; k0 < K; k0 += 32) {
        short8 a = *(const short8*)&Xs[arow * LDX + k0 + q * 8];
#pragma unroll
        for (int t = 0; t < 8; ++t) {
            short8 b = *(const short8*)&Ws[(t * 16 + m) * LDX + k0 + q * 8];
            acc[t] = __builtin_amdgcn_mfma_f32_16x16x32_bf16(a, b, acc[t], 0, 0, 0);
        }
    }

    // C/D layout: col = lane&15 (within tile), row = q*4 + reg.
    // head0 = tiles 0..3 (cols 0..63), head1 = tiles 4..7 (cols 64..127).
    const int rbase = row0 + wv * 16 + q * 4;
#pragma unroll
    for (int t = 0; t < 4; ++t) {
#pragma unroll
        for (int r = 0; r < 4; ++r) {
            int gr = rbase + r;
            if (gr < N) {
                unsigned int z0 = f2bf(acc[t][r]);
                unsigned int z1 = f2bf(acc[t + 4][r]);
                Zg[(size_t)gr * 64 + t * 16 + m] = z0 | (z1 << 16);
            }
        }
    }
}

// ---------------- attention coefficients ----------------
__global__ __launch_bounds__(256) void attn_coeff(const unsigned int* __restrict__ Zg,
                                                  const float* __restrict__ al,
                                                  const float* __restrict__ ar,
                                                  float* __restrict__ el,
                                                  float* __restrict__ er, int N) {
    int wv = (blockIdx.x * blockDim.x + threadIdx.x) >> 6;
    int lane = threadIdx.x & 63;
    if (wv >= N) return;
    unsigned int p = Zg[(size_t)wv * 64 + lane];
    float z0 = bf2f(p & 0xffffu);
    float z1 = bf2f(p >> 16);
    float pl0 = z0 * al[lane];
    float pl1 = z1 * al[64 + lane];
    float pr0 = z0 * ar[lane];
    float pr1 = z1 * ar[64 + lane];
    for (int off = 32; off; off >>= 1) {
        pl0 += __shfl_xor(pl0, off);
        pl1 += __shfl_xor(pl1, off);
        pr0 += __shfl_xor(pr0, off);
        pr1 += __shfl_xor(pr1, off);
    }
    if (lane == 0) {
        el[2 * wv] = pl0;
        el[2 * wv + 1] = pl1;
        er[2 * wv] = pr0;
        er[2 * wv + 1] = pr1;
    }
}

// ---------------- aggregate: edge softmax + gather ----------------
// One wave per dst node. Zg packed bf16 pairs: one dword gather per lane/edge.
__global__ __launch_bounds__(256) void aggregate(
    const unsigned int* __restrict__ Zg, const float* __restrict__ el,
    const float* __restrict__ er, const int* __restrict__ row_start,
    const int* __restrict__ esrc, const float* __restrict__ bias,
    const float* __restrict__ gamma, const float* __restrict__ beta,
    unsigned short* __restrict__ out_bf, float* __restrict__ out_f,
    int N, int do_ln) {
    int wv = (blockIdx.x * blockDim.x + threadIdx.x) >> 6;
    int lane = threadIdx.x & 63;
    if (wv >= N) return;
    int s0 = row_start[wv], s1 = row_start[wv + 1];
    float er0 = er[2 * wv], er1 = er[2 * wv + 1];

    // pass 1: softmax denominators (no max-shift needed: |e| small, fp32 exp safe)
    float denom0 = 0.f, denom1 = 0.f;
    for (int base = s0; base < s1; base += 64) {
        int idx = base + lane;
        float w0 = 0.f, w1 = 0.f;
        if (idx < s1) {
            int sv = esrc[idx];
            float e0 = el[2 * sv] + er0;
            e0 = e0 > 0.f ? e0 : 0.2f * e0;
            float e1 = el[2 * sv + 1] + er1;
            e1 = e1 > 0.f ? e1 : 0.2f * e1;
            w0 = __expf(e0);
            w1 = __expf(e1);
        }
        float t0 = w0, t1 = w1;
        for (int off = 32; off; off >>= 1) {
            t0 += __shfl_xor(t0, off);
            t1 += __shfl_xor(t1, off);
        }
        denom0 += t0;
        denom1 += t1;
    }
    float inv0 = denom0 > 0.f ? 1.f / denom0 : 0.f;
    float inv1 = denom1 > 0.f ? 1.f / denom1 : 0.f;

    // pass 2: weighted gather
    float acc0 = 0.f, acc1 = 0.f;
    for (int base = s0; base < s1; base += 64) {
        int idx = base + lane;
        int sv = 0;
        float w0 = 0.f, w1 = 0.f;
        if (idx < s1) {
            sv = esrc[idx];
            float e0 = el[2 * sv] + er0;
            e0 = e0 > 0.f ? e0 : 0.2f * e0;
            float e1 = el[2 * sv + 1] + er1;
            e1 = e1 > 0.f ? e1 : 0.2f * e1;
            w0 = __expf(e0);
            w1 = __expf(e1);
        }
        int mm = min(64, s1 - base);
        for (int j = 0; j < mm; ++j) {
            int svj = __shfl(sv, j);
            float a0 = __shfl(w0, j) * inv0;
            float a1 = __shfl(w1, j) * inv1;
            unsigned int p = Zg[(size_t)svj * 64 + lane];
            acc0 += a0 * bf2f(p & 0xffffu);
            acc1 += a1 * bf2f(p >> 16);
        }
    }

    float m0 = (acc0 + acc1) * 0.5f + 0.5f * (bias[lane] + bias[64 + lane]);
    if (do_ln) {
        float s = m0;
        for (int off = 32; off; off >>= 1) s += __shfl_xor(s, off);
        float mu = s * (1.f / 64.f);
        float d = m0 - mu;
        float v = d * d;
        for (int off = 32; off; off >>= 1) v += __shfl_xor(v, off);
        float rstd = rsqrtf(v * (1.f / 64.f) + 1e-5f);
        float y = d * rstd * gamma[lane] + beta[lane];
        y = y > 0.f ? y : 0.f;
        out_bf[(size_t)wv * 64 + lane] = (unsigned short)f2bf(y);
    } else {
        out_f[(size_t)wv * 64 + lane] = m0;
    }
}

// ---------------------------------------------------------------------------
static inline char* align_up(char* p, size_t a) {
    return (char*)(((uintptr_t)p + a - 1) & ~(uintptr_t)(a - 1));
}

extern "C" void kernel_launch(void* const* d_in, const int* in_sizes, int n_in,
                              void* d_out, int out_size, void* d_ws, size_t ws_size,
                              hipStream_t stream) {
    const float* feat = (const float*)d_in[0];
    const int* src = (const int*)d_in[1];
    const int* dst = (const int*)d_in[2];
    const float* W1 = (const float*)d_in[3];
    const float* al1 = (const float*)d_in[4];
    const float* ar1 = (const float*)d_in[5];
    const float* b1 = (const float*)d_in[6];
    const float* gamma1 = (const float*)d_in[7];
    const float* beta1 = (const float*)d_in[8];
    const float* W2 = (const float*)d_in[9];
    const float* al2 = (const float*)d_in[10];
    const float* ar2 = (const float*)d_in[11];
    const float* b2 = (const float*)d_in[12];

    const int N = in_sizes[0] / 128;
    const int E = in_sizes[1];

    char* p = (char*)d_ws;
    unsigned int* Zg = (unsigned int*)p;            p += (size_t)N * 64 * 4;
    float* el = (float*)p;                          p += (size_t)2 * N * 4;
    float* er = (float*)p;                          p += (size_t)2 * N * 4;
    int* counts = (int*)p;                          p += (size_t)N * 4;
    int* row_start = (int*)p;                       p += (size_t)(N + 1) * 4;
    int* cursor = (int*)p;                          p += (size_t)N * 4;
    int* bsum = (int*)p;                            p += 1024 * 4;
    int* esrc = (int*)p;                            p += (size_t)E * 4;
    p = align_up(p, 64);
    unsigned short* featb = (unsigned short*)p;     p += (size_t)N * 128 * 2;
    p = align_up(p, 64);
    unsigned short* hb = (unsigned short*)p;        p += (size_t)N * 64 * 2;
    p = align_up(p, 64);
    unsigned short* W1t = (unsigned short*)p;       p += 128 * 128 * 2;
    unsigned short* W2t = (unsigned short*)p;       p += 128 * 64 * 2;

    const int nb = (N + 1023) / 1024;

    // casts
    cast_feat<<<(N * 128 / 4 + 255) / 256, 256, 0, stream>>>(feat, featb, N * 128 / 4);
    cast_w_t<<<(128 * 128 + 255) / 256, 256, 0, stream>>>(W1, W1t, 128);
    cast_w_t<<<(64 * 128 + 255) / 256, 256, 0, stream>>>(W2, W2t, 64);

    // CSR build (shared by both layers)
    hipMemsetAsync(counts, 0, sizeof(int) * N, stream);
    count_deg<<<(E + 255) / 256, 256, 0, stream>>>(dst, counts, E);
    scan1<<<nb, 1024, 0, stream>>>(counts, row_start, bsum, N);
    scan2<<<1, 1024, 0, stream>>>(bsum, nb);
    scan3<<<nb, 1024, 0, stream>>>(row_start, bsum, cursor, N, E);
    fill_edges<<<(E + 255) / 256, 256, 0, stream>>>(src, dst, cursor, esrc, E);

    // layer 0
    gemm_mfma<128><<<(N + 63) / 64, 256, 0, stream>>>(featb, W1t, Zg, N);
    attn_coeff<<<(N + 3) / 4, 256, 0, stream>>>(Zg, al1, ar1, el, er, N);
    aggregate<<<(N + 3) / 4, 256, 0, stream>>>(Zg, el, er, row_start, esrc, b1,
                                               gamma1, beta1, hb, nullptr, N, 1);

    // layer 1
    gemm_mfma<64><<<(N + 63) / 64, 256, 0, stream>>>(hb, W2t, Zg, N);
    attn_coeff<<<(N + 3) / 4, 256, 0, stream>>>(Zg, al2, ar2, el, er, N);
    aggregate<<<(N + 3) / 4, 256, 0, stream>>>(Zg, el, er, row_start, esrc, b2,
                                               nullptr, nullptr, nullptr, (float*)d_out, N, 0);
}

// Round 3
// 334.828 us; speedup vs baseline: 1.6149x; 1.3660x over previous
//
#include <hip/hip_runtime.h>

// ---------------------------------------------------------------------------
// 2-layer GAT (H=2, D=64, Fin=128) on MI355X.
// bf16 MFMA GEMMs with fused attention-coefficient epilogue, packed-bf16 Z,
// single-pass edge-softmax aggregation with 4-wide unrolled gathers.
// ---------------------------------------------------------------------------

typedef __attribute__((ext_vector_type(8))) short short8;
typedef __attribute__((ext_vector_type(8))) unsigned short ushort8;
typedef __attribute__((ext_vector_type(4))) float f32x4;

__device__ inline unsigned int f2bf(float x) {
    unsigned int u = __builtin_bit_cast(unsigned int, x);
    return (u + 0x7fffu + ((u >> 16) & 1u)) >> 16;   // RNE
}
__device__ inline float bflo(unsigned int u) {       // low bf16 -> f32
    return __builtin_bit_cast(float, u << 16);
}
__device__ inline float bfhi(unsigned int u) {       // high bf16 -> f32
    return __builtin_bit_cast(float, u & 0xffff0000u);
}
__device__ inline float rlanef(float v, int l) {
    return __builtin_bit_cast(float, __builtin_amdgcn_readlane(__builtin_bit_cast(int, v), l));
}

// ---------------- fused init: casts + transposes + zero counts -------------
__global__ __launch_bounds__(256) void init_fused(
    const float* __restrict__ feat, unsigned short* __restrict__ featb,
    const float* __restrict__ W1, unsigned short* __restrict__ W1t,
    const float* __restrict__ W2, unsigned short* __restrict__ W2t,
    int* __restrict__ counts, int N) {
    int i = blockIdx.x * 256 + threadIdx.x;
    const int nf4 = N * 32;  // N*128/4 float4 groups
    if (i < nf4) {
        float4 v = ((const float4*)feat)[i];
        ushort4 o = {(unsigned short)f2bf(v.x), (unsigned short)f2bf(v.y),
                     (unsigned short)f2bf(v.z), (unsigned short)f2bf(v.w)};
        ((ushort4*)featb)[i] = o;
        return;
    }
    int j = i - nf4;
    if (j < 128 * 128) {  // W1[k][c] -> W1t[c][k]
        int k = j >> 7, c = j & 127;
        W1t[c * 128 + k] = (unsigned short)f2bf(W1[j]);
        return;
    }
    int l = j - 128 * 128;
    if (l < 64 * 128) {   // W2[k][c] -> W2t[c][k]
        int k = l >> 7, c = l & 127;
        W2t[c * 64 + k] = (unsigned short)f2bf(W2[l]);
        return;
    }
    int q = l - 64 * 128;
    if (q < N) counts[q] = 0;
}

// ---------------- CSR build ----------------
__global__ __launch_bounds__(256) void count_deg(const int* __restrict__ dst,
                                                 int* __restrict__ counts, int E) {
    int i = blockIdx.x * blockDim.x + threadIdx.x;
    if (i < E) atomicAdd(&counts[dst[i]], 1);
}

__global__ __launch_bounds__(1024) void scan1(const int* __restrict__ counts,
                                              int* __restrict__ excl,
                                              int* __restrict__ bsum, int N) {
    __shared__ int s[1024];
    int tid = threadIdx.x;
    int gid = blockIdx.x * 1024 + tid;
    int v = (gid < N) ? counts[gid] : 0;
    s[tid] = v;
    __syncthreads();
    for (int off = 1; off < 1024; off <<= 1) {
        int t = (tid >= off) ? s[tid - off] : 0;
        __syncthreads();
        s[tid] += t;
        __syncthreads();
    }
    if (gid < N) excl[gid] = s[tid] - v;
    if (tid == 1023) bsum[blockIdx.x] = s[1023];
}

__global__ __launch_bounds__(1024) void scan2(int* __restrict__ bsum, int nb) {
    __shared__ int s[1024];
    int tid = threadIdx.x;
    int v = (tid < nb) ? bsum[tid] : 0;
    s[tid] = v;
    __syncthreads();
    for (int off = 1; off < 1024; off <<= 1) {
        int t = (tid >= off) ? s[tid - off] : 0;
        __syncthreads();
        s[tid] += t;
        __syncthreads();
    }
    if (tid < nb) bsum[tid] = s[tid] - v;
}

__global__ __launch_bounds__(1024) void scan3(int* __restrict__ excl_inout,
                                              const int* __restrict__ bsum,
                                              int* __restrict__ cursor, int N, int E) {
    int gid = blockIdx.x * 1024 + threadIdx.x;
    if (gid < N) {
        int v = excl_inout[gid] + bsum[blockIdx.x];
        excl_inout[gid] = v;
        cursor[gid] = v;
    }
    if (gid == 0) excl_inout[N] = E;
}

__global__ __launch_bounds__(256) void fill_edges(const int* __restrict__ src,
                                                  const int* __restrict__ dst,
                                                  int* __restrict__ cursor,
                                                  int* __restrict__ esrc, int E) {
    int i = blockIdx.x * blockDim.x + threadIdx.x;
    if (i < E) {
        int p = atomicAdd(&cursor[dst[i]], 1);
        esrc[p] = src[i];
    }
}

// ---------------- MFMA GEMM + fused attn-coefficient epilogue --------------
// Zg[n][f] = pack(bf16 z[n][f], bf16 z[n][64+f]); el2/er2[n] = (head0, head1).
template <int K>
__global__ __launch_bounds__(256) void gemm_mfma(
    const unsigned short* __restrict__ Xb, const unsigned short* __restrict__ Wt,
    const float* __restrict__ al, const float* __restrict__ ar,
    unsigned int* __restrict__ Zg, float2* __restrict__ el2,
    float2* __restrict__ er2, int N) {
    constexpr int LDX = K + 8;
    __shared__ unsigned short Ws[128 * LDX];
    __shared__ unsigned short Xs[64 * LDX];
    const int tid = threadIdx.x;
    const int row0 = blockIdx.x * 64;

    constexpr int KC = K / 8;
    for (int i = tid; i < 128 * KC; i += 256) {
        int r = i / KC, c8 = i % KC;
        ushort8 v = *(const ushort8*)&Wt[r * K + c8 * 8];
        *(ushort8*)&Ws[r * LDX + c8 * 8] = v;
    }
    for (int i = tid; i < 64 * KC; i += 256) {
        int r = i / KC, c8 = i % KC;
        int gr = row0 + r;
        int sr = (gr < N) ? gr : 0;
        ushort8 v = *(const ushort8*)&Xb[(size_t)sr * K + c8 * 8];
        *(ushort8*)&Xs[r * LDX + c8 * 8] = v;
    }
    __syncthreads();

    const int wv = tid >> 6, lane = tid & 63;
    const int m = lane & 15, q = lane >> 4;

    f32x4 acc[8];
#pragma unroll
    for (int t = 0; t < 8; ++t) {
        acc[t][0] = 0.f; acc[t][1] = 0.f; acc[t][2] = 0.f; acc[t][3] = 0.f;
    }

    const int arow = wv * 16 + m;
#pragma unroll
    for (int k0 = 0; k0 < K; k0 += 32) {
        short8 a = *(const short8*)&Xs[arow * LDX + k0 + q * 8];
#pragma unroll
        for (int t = 0; t < 8; ++t) {
            short8 b = *(const short8*)&Ws[(t * 16 + m) * LDX + k0 + q * 8];
            acc[t] = __builtin_amdgcn_mfma_f32_16x16x32_bf16(a, b, acc[t], 0, 0, 0);
        }
    }

    // acc[t][r] = Z[row0 + wv*16 + q*4 + r][t*16 + m]
    const int rbase = row0 + wv * 16 + q * 4;

    // store packed Z
#pragma unroll
    for (int t = 0; t < 4; ++t) {
#pragma unroll
        for (int r = 0; r < 4; ++r) {
            int gr = rbase + r;
            if (gr < N) {
                unsigned int z0 = f2bf(acc[t][r]);
                unsigned int z1 = f2bf(acc[t + 4][r]);
                Zg[(size_t)gr * 64 + t * 16 + m] = z0 | (z1 << 16);
            }
        }
    }

    // fused attn coefficients: al[64 + (t-4)*16 + m] == al[t*16+m], so one table.
    float alv[8], arv[8];
#pragma unroll
    for (int t = 0; t < 8; ++t) {
        alv[t] = al[t * 16 + m];
        arv[t] = ar[t * 16 + m];
    }
#pragma unroll
    for (int r = 0; r < 4; ++r) {
        float pel0 = 0.f, pel1 = 0.f, per0 = 0.f, per1 = 0.f;
#pragma unroll
        for (int t = 0; t < 4; ++t) {
            pel0 += acc[t][r] * alv[t];
            per0 += acc[t][r] * arv[t];
            pel1 += acc[t + 4][r] * alv[t + 4];
            per1 += acc[t + 4][r] * arv[t + 4];
        }
#pragma unroll
        for (int off = 1; off < 16; off <<= 1) {
            pel0 += __shfl_xor(pel0, off);
            pel1 += __shfl_xor(pel1, off);
            per0 += __shfl_xor(per0, off);
            per1 += __shfl_xor(per1, off);
        }
        int gr = rbase + r;
        if (m == 0 && gr < N) {
            el2[gr] = make_float2(pel0, pel1);
            er2[gr] = make_float2(per0, per1);
        }
    }
}

// ---------------- aggregate: single-pass edge softmax + gather -------------
// One wave per dst node. out = (Σ w_j z_j) / (Σ w_j); scale applied at end.
__global__ __launch_bounds__(256) void aggregate(
    const unsigned int* __restrict__ Zg, const float2* __restrict__ el2,
    const float2* __restrict__ er2, const int* __restrict__ row_start,
    const int* __restrict__ esrc, const float* __restrict__ bias,
    const float* __restrict__ gamma, const float* __restrict__ beta,
    unsigned short* __restrict__ out_bf, float* __restrict__ out_f,
    int N, int do_ln) {
    int wv = (blockIdx.x * blockDim.x + threadIdx.x) >> 6;
    int lane = threadIdx.x & 63;
    if (wv >= N) return;
    int s0 = row_start[wv], s1 = row_start[wv + 1];
    float2 er = er2[wv];

    float acc0 = 0.f, acc1 = 0.f, dsum0 = 0.f, dsum1 = 0.f;
    for (int base = s0; base < s1; base += 64) {
        int idx = base + lane;
        int sv = 0;
        float w0 = 0.f, w1 = 0.f;
        if (idx < s1) {
            sv = esrc[idx];
            float2 elv = el2[sv];
            float e0 = elv.x + er.x;
            e0 = e0 > 0.f ? e0 : 0.2f * e0;
            float e1 = elv.y + er.y;
            e1 = e1 > 0.f ? e1 : 0.2f * e1;
            w0 = __expf(e0);
            w1 = __expf(e1);
        }
        dsum0 += w0;
        dsum1 += w1;
        int mm = min(64, s1 - base);
        int j = 0;
        for (; j + 4 <= mm; j += 4) {
            int sa = __builtin_amdgcn_readlane(sv, j);
            int sb = __builtin_amdgcn_readlane(sv, j + 1);
            int sc = __builtin_amdgcn_readlane(sv, j + 2);
            int sd = __builtin_amdgcn_readlane(sv, j + 3);
            float wa0 = rlanef(w0, j), wa1 = rlanef(w1, j);
            float wb0 = rlanef(w0, j + 1), wb1 = rlanef(w1, j + 1);
            float wc0 = rlanef(w0, j + 2), wc1 = rlanef(w1, j + 2);
            float wd0 = rlanef(w0, j + 3), wd1 = rlanef(w1, j + 3);
            unsigned int ua = Zg[(size_t)sa * 64 + lane];
            unsigned int ub = Zg[(size_t)sb * 64 + lane];
            unsigned int uc = Zg[(size_t)sc * 64 + lane];
            unsigned int ud = Zg[(size_t)sd * 64 + lane];
            acc0 += wa0 * bflo(ua);
            acc1 += wa1 * bfhi(ua);
            acc0 += wb0 * bflo(ub);
            acc1 += wb1 * bfhi(ub);
            acc0 += wc0 * bflo(uc);
            acc1 += wc1 * bfhi(uc);
            acc0 += wd0 * bflo(ud);
            acc1 += wd1 * bfhi(ud);
        }
        for (; j < mm; ++j) {
            int sj = __builtin_amdgcn_readlane(sv, j);
            float wj0 = rlanef(w0, j), wj1 = rlanef(w1, j);
            unsigned int u = Zg[(size_t)sj * 64 + lane];
            acc0 += wj0 * bflo(u);
            acc1 += wj1 * bfhi(u);
        }
    }
    for (int off = 32; off; off >>= 1) {
        dsum0 += __shfl_xor(dsum0, off);
        dsum1 += __shfl_xor(dsum1, off);
    }
    float inv0 = dsum0 > 0.f ? 1.f / dsum0 : 0.f;
    float inv1 = dsum1 > 0.f ? 1.f / dsum1 : 0.f;

    float m0 = (acc0 * inv0 + acc1 * inv1) * 0.5f + 0.5f * (bias[lane] + bias[64 + lane]);
    if (do_ln) {
        float s = m0;
        for (int off = 32; off; off >>= 1) s += __shfl_xor(s, off);
        float mu = s * (1.f / 64.f);
        float d = m0 - mu;
        float v = d * d;
        for (int off = 32; off; off >>= 1) v += __shfl_xor(v, off);
        float rstd = rsqrtf(v * (1.f / 64.f) + 1e-5f);
        float y = d * rstd * gamma[lane] + beta[lane];
        y = y > 0.f ? y : 0.f;
        out_bf[(size_t)wv * 64 + lane] = (unsigned short)f2bf(y);
    } else {
        out_f[(size_t)wv * 64 + lane] = m0;
    }
}

// ---------------------------------------------------------------------------
static inline char* align_up(char* p, size_t a) {
    return (char*)(((uintptr_t)p + a - 1) & ~(uintptr_t)(a - 1));
}

extern "C" void kernel_launch(void* const* d_in, const int* in_sizes, int n_in,
                              void* d_out, int out_size, void* d_ws, size_t ws_size,
                              hipStream_t stream) {
    const float* feat = (const float*)d_in[0];
    const int* src = (const int*)d_in[1];
    const int* dst = (const int*)d_in[2];
    const float* W1 = (const float*)d_in[3];
    const float* al1 = (const float*)d_in[4];
    const float* ar1 = (const float*)d_in[5];
    const float* b1 = (const float*)d_in[6];
    const float* gamma1 = (const float*)d_in[7];
    const float* beta1 = (const float*)d_in[8];
    const float* W2 = (const float*)d_in[9];
    const float* al2 = (const float*)d_in[10];
    const float* ar2 = (const float*)d_in[11];
    const float* b2 = (const float*)d_in[12];

    const int N = in_sizes[0] / 128;
    const int E = in_sizes[1];

    char* p = (char*)d_ws;
    unsigned int* Zg = (unsigned int*)p;            p += (size_t)N * 64 * 4;
    float2* el2 = (float2*)p;                       p += (size_t)N * 8;
    float2* er2 = (float2*)p;                       p += (size_t)N * 8;
    int* counts = (int*)p;                          p += (size_t)N * 4;
    int* row_start = (int*)p;                       p += (size_t)(N + 1) * 4;
    int* cursor = (int*)p;                          p += (size_t)N * 4;
    int* bsum = (int*)p;                            p += 1024 * 4;
    int* esrc = (int*)p;                            p += (size_t)E * 4;
    p = align_up(p, 64);
    unsigned short* featb = (unsigned short*)p;     p += (size_t)N * 128 * 2;
    p = align_up(p, 64);
    unsigned short* hb = (unsigned short*)p;        p += (size_t)N * 64 * 2;
    p = align_up(p, 64);
    unsigned short* W1t = (unsigned short*)p;       p += 128 * 128 * 2;
    unsigned short* W2t = (unsigned short*)p;       p += 128 * 64 * 2;

    const int nb = (N + 1023) / 1024;
    const int init_work = N * 32 + 128 * 128 + 64 * 128 + N;

    init_fused<<<(init_work + 255) / 256, 256, 0, stream>>>(feat, featb, W1, W1t,
                                                            W2, W2t, counts, N);
    count_deg<<<(E + 255) / 256, 256, 0, stream>>>(dst, counts, E);
    scan1<<<nb, 1024, 0, stream>>>(counts, row_start, bsum, N);
    scan2<<<1, 1024, 0, stream>>>(bsum, nb);
    scan3<<<nb, 1024, 0, stream>>>(row_start, bsum, cursor, N, E);
    fill_edges<<<(E + 255) / 256, 256, 0, stream>>>(src, dst, cursor, esrc, E);

    // layer 0
    gemm_mfma<128><<<(N + 63) / 64, 256, 0, stream>>>(featb, W1t, al1, ar1,
                                                      Zg, el2, er2, N);
    aggregate<<<(N + 3) / 4, 256, 0, stream>>>(Zg, el2, er2, row_start, esrc, b1,
                                               gamma1, beta1, hb, nullptr, N, 1);

    // layer 1
    gemm_mfma<64><<<(N + 63) / 64, 256, 0, stream>>>(hb, W2t, al2, ar2,
                                                     Zg, el2, er2, N);
    aggregate<<<(N + 3) / 4, 256, 0, stream>>>(Zg, el2, er2, row_start, esrc, b2,
                                               nullptr, nullptr, nullptr, (float*)d_out, N, 0);
}